// Round 14
// baseline (418.806 us; speedup 1.0000x reference)
//
#include <hip/hip_runtime.h>
#include <math.h>

#define NUM_K 1024
#define DIM 256
#define HW 4096          // 64*64
#define NPIX 65536       // 16*4096
#define QELEMS 16777216  // 16*256*4096
#define MAX_FLAGS 16384

typedef short bf16x8 __attribute__((ext_vector_type(8)));
typedef float f32x4 __attribute__((ext_vector_type(4)));

__device__ __forceinline__ unsigned short f32_to_bf16_rne(float f) {
    unsigned int u = __float_as_uint(f);
    unsigned int r = u + 0x7FFFu + ((u >> 16) & 1u);
    return (unsigned short)(r >> 16);
}

// merge two lex-sorted top-3 states (proven rounds 9-13, absmax 0)
__device__ __forceinline__ void merge3(float& a1d, int& a1i, float& a2d, int& a2i, float& a3d,
                                       float b1d, int b1i, float b2d, int b2i, float b3d) {
    bool bf = (b1d < a1d) || (b1d == a1d && b1i < a1i);
    float r1d = bf ? b1d : a1d; int r1i = bf ? b1i : a1i;
    float n2d = bf ? b2d : a2d; int n2i = bf ? b2i : a2i;
    float o1d = bf ? a1d : b1d; int o1i = bf ? a1i : b1i;
    bool k2 = (n2d < o1d) || (n2d == o1d && n2i < o1i);
    float r2d = k2 ? n2d : o1d; int r2i = k2 ? n2i : o1i;
    float sm3 = bf ? b3d : a3d;
    float o2d = bf ? a2d : b2d;
    float r3d = k2 ? fminf(sm3, o1d) : fminf(n2d, o2d);
    a1d = r1d; a1i = r1i; a2d = r2d; a2i = r2i; a3d = r3d;
}

// ---------------------------------------------------------------------------
// numpy-replicated f32 sum of squares (pairwise SIMD tree, proven rounds 2-13)
// ---------------------------------------------------------------------------
__device__ __forceinline__ float np_sumsq_256(const float* __restrict__ p, long stride) {
    float blk0 = 0.f, blk1 = 0.f;
#pragma unroll
    for (int h = 0; h < 2; ++h) {
        const float* base = p + (long)h * 128 * stride;
        float s[16];
#pragma unroll
        for (int L = 0; L < 16; ++L) {
            float a0 = base[(long)(L)       * stride]; a0 = __fmul_rn(a0, a0);
            float a1 = base[(long)(16 + L)  * stride]; a1 = __fmul_rn(a1, a1);
            float a2 = base[(long)(32 + L)  * stride]; a2 = __fmul_rn(a2, a2);
            float a3 = base[(long)(48 + L)  * stride]; a3 = __fmul_rn(a3, a3);
            float a4 = base[(long)(64 + L)  * stride]; a4 = __fmul_rn(a4, a4);
            float a5 = base[(long)(80 + L)  * stride]; a5 = __fmul_rn(a5, a5);
            float a6 = base[(long)(96 + L)  * stride]; a6 = __fmul_rn(a6, a6);
            float a7 = base[(long)(112 + L) * stride]; a7 = __fmul_rn(a7, a7);
            float t1 = __fadd_rn(a0, a1);
            float t2 = __fadd_rn(a2, a3);
            float t3 = __fadd_rn(a4, a5);
            float t4 = __fadd_rn(a6, a7);
            s[L] = __fadd_rn(__fadd_rn(t1, t2), __fadd_rn(t3, t4));
        }
        float c0 = __fadd_rn(s[0], s[8]);
        float c1 = __fadd_rn(s[1], s[9]);
        float c2 = __fadd_rn(s[2], s[10]);
        float c3 = __fadd_rn(s[3], s[11]);
        float c4 = __fadd_rn(s[4], s[12]);
        float c5 = __fadd_rn(s[5], s[13]);
        float c6 = __fadd_rn(s[6], s[14]);
        float c7 = __fadd_rn(s[7], s[15]);
        float d0 = __fadd_rn(c0, c4);
        float d1 = __fadd_rn(c1, c5);
        float d2 = __fadd_rn(c2, c6);
        float d3 = __fadd_rn(c3, c7);
        float e0 = __fadd_rn(d0, d2);
        float e1 = __fadd_rn(d1, d3);
        float r  = __fadd_rn(e0, e1);
        if (h == 0) blk0 = r; else blk1 = r;
    }
    return __fadd_rn(blk0, blk1);
}

// ---------------------------------------------------------------------------
// fused prep: blocks 0..127 wfrag, 128..255 wtrans, 256..259 wsq (+zero init)
// ---------------------------------------------------------------------------
__global__ __launch_bounds__(256)
void k_prep(const float* __restrict__ w, float* __restrict__ wsq,
            float* __restrict__ wtr, short* __restrict__ whi,
            float* __restrict__ loss, int* __restrict__ paircnt, int* __restrict__ fullcnt) {
    const int bk = blockIdx.x;
    const int t = threadIdx.x;
    if (bk < 128) {
        // w -> frag-major bf16 (hi only)
        int id = bk * 256 + t;                 // 32768 = 1024 codes * 32 chunks
        int code = id >> 5;
        int c = id & 31;
        const float* src = w + (long)code * DIM + c * 8;
        bf16x8 vh;
#pragma unroll
        for (int j = 0; j < 8; ++j) vh[j] = (short)f32_to_bf16_rne(src[j]);
        int fl = ((c & 3) << 4) | (code & 15);
        long addr = ((((long)(code >> 4) * 8 + (c >> 2)) * 64 + fl) * 8);
        *(bf16x8*)(whi + addr) = vh;
    } else if (bk < 256) {
        // wtr[d][k] = w[k][d]
        int d0 = (bk - 128) * 2;
#pragma unroll
        for (int dd = 0; dd < 2; ++dd) {
            int d = d0 + dd;
#pragma unroll
            for (int kk = 0; kk < 4; ++kk) {
                int k = kk * 256 + t;
                wtr[(long)d * NUM_K + k] = w[(long)k * DIM + d];
            }
        }
    } else {
        int k = (bk - 256) * 256 + t;
        wsq[k] = np_sumsq_256(w + (long)k * DIM, 1);
        if (bk == 256 && t == 0) { *loss = 0.f; *paircnt = 0; *fullcnt = 0; }
    }
}

// fallback-only (main path fuses xsq into argmin)
__global__ __launch_bounds__(256) void k_xsq(const float* __restrict__ x, float* __restrict__ xsq) {
    int n = blockIdx.x * 256 + threadIdx.x;
    int b = n >> 12, hw = n & 4095;
    xsq[n] = np_sumsq_256(x + (long)b * DIM * HW + hw, HW);
}

// ---------------------------------------------------------------------------
// MFMA argmin v14 = v13 merged structure + single-butterfly epilogue:
// per-lane top-3 state persists across BOTH K-sweeps (strict-< insert in
// ascending code order == same lex top-3), butterfly + LDS merge run ONCE.
// Ring stays depth 4 (registers: 128 VGPR + 128 AGPR = exactly the 2-wave
// boundary; rounds 5/10 proved the cliff beyond it).
// ---------------------------------------------------------------------------
#define A_SLOT(ks,m,fl) ((((ks)*4+(m))*64+(fl))*8)

__global__ __launch_bounds__(256, 2)
void k_argmin_mfma(const float* __restrict__ x,
                   const short* __restrict__ whi,
                   const float* __restrict__ wsq, float* __restrict__ xsq,
                   int* __restrict__ idx,
                   int4* __restrict__ pairf, int* __restrict__ paircnt,
                   int* __restrict__ fullf, int* __restrict__ fullcnt) {
    __shared__ short ahi[8 * 4 * 64 * 8];      // 32KB [ks][m][fl][j]
    __shared__ float xpart[4 * 16 * 64];       // 16KB [q][L][px] numpy-tree partials
    __shared__ float xsq_s[64];
    __shared__ float cd1[4][64], cd2[4][64], cd3[4][64];
    __shared__ int   ci1[4][64], ci2[4][64];

    const int t = threadIdx.x;
    const int lane = t & 63;
    const int q = t >> 6;
    const int tile = blockIdx.x;               // 1024 tiles of 64 px
    const int b = tile >> 6;
    const int hw0 = (tile & 63) * 64;
    const long px0 = (long)tile * 64;
    const float* xb = x + (long)b * (DIM * HW) + hw0 + lane;

    // ---- stage A (once) + numpy-tree square partials (proven rounds 12-13) ----
    {
        float tmp[16], part[16];
#pragma unroll
        for (int i = 0; i < 8; ++i) {
            int c = q * 8 + i;                 // d-chunk: d = c*8 + jj
            float v[8];
#pragma unroll
            for (int jj = 0; jj < 8; ++jj) v[jj] = xb[(long)(c * 8 + jj) * HW];
            bf16x8 vh;
#pragma unroll
            for (int jj = 0; jj < 8; ++jj) vh[jj] = (short)f32_to_bf16_rne(v[jj]);
            int slot = A_SLOT(c >> 2, lane >> 4, ((c & 3) << 4) | (lane & 15));
            *(bf16x8*)(ahi + slot) = vh;
            const int kp = i >> 1;
#pragma unroll
            for (int jj = 0; jj < 8; ++jj) {
                int L = ((i & 1) << 3) | jj;
                float a = __fmul_rn(v[jj], v[jj]);
                if (kp == 0) tmp[L] = a;
                else if (kp == 1) part[L] = __fadd_rn(tmp[L], a);
                else if (kp == 2) tmp[L] = a;
                else part[L] = __fadd_rn(part[L], __fadd_rn(tmp[L], a));
            }
        }
#pragma unroll
        for (int L = 0; L < 16; ++L) xpart[(q * 16 + L) * 64 + lane] = part[L];
    }
    __syncthreads();

    // ---- finisher: complete np_sumsq per pixel (t<64), LDS + global ----
    if (t < 64) {
        float blk[2];
#pragma unroll
        for (int h = 0; h < 2; ++h) {
            float s[16];
#pragma unroll
            for (int L = 0; L < 16; ++L)
                s[L] = __fadd_rn(xpart[((2 * h) * 16 + L) * 64 + t],
                                 xpart[((2 * h + 1) * 16 + L) * 64 + t]);
            float c0 = __fadd_rn(s[0], s[8]);
            float c1 = __fadd_rn(s[1], s[9]);
            float c2 = __fadd_rn(s[2], s[10]);
            float c3 = __fadd_rn(s[3], s[11]);
            float c4 = __fadd_rn(s[4], s[12]);
            float c5 = __fadd_rn(s[5], s[13]);
            float c6 = __fadd_rn(s[6], s[14]);
            float c7 = __fadd_rn(s[7], s[15]);
            float d0 = __fadd_rn(c0, c4);
            float d1 = __fadd_rn(c1, c5);
            float d2 = __fadd_rn(c2, c6);
            float d3 = __fadd_rn(c3, c7);
            float e0 = __fadd_rn(d0, d2);
            float e1 = __fadd_rn(d1, d3);
            blk[h] = __fadd_rn(e0, e1);
        }
        float v = __fadd_rn(blk[0], blk[1]);
        xsq_s[t] = v;
        xsq[px0 + t] = v;                      // for the exact-refine kernels
    }
    __syncthreads();

    // ---- persistent per-lane top-3 across BOTH sweeps ----
    const int rbase = (lane >> 4) * 4;
    float s1v[4][4];
#pragma unroll
    for (int m = 0; m < 4; ++m)
#pragma unroll
        for (int r = 0; r < 4; ++r) s1v[m][r] = xsq_s[16 * m + rbase + r];

    float e1d[4][4], e2d[4][4], e3d[4][4];
    int   e1i[4][4], e2i[4][4];
#pragma unroll
    for (int m = 0; m < 4; ++m)
#pragma unroll
        for (int r = 0; r < 4; ++r) {
            e1d[m][r] = INFINITY; e2d[m][r] = INFINITY; e3d[m][r] = INFINITY;
            e1i[m][r] = 0; e2i[m][r] = 0;
        }

#pragma unroll
    for (int s = 0; s < 2; ++s) {
        const int ct0 = s * 32 + q * 8;
        f32x4 acc[4][8];
#pragma unroll
        for (int m = 0; m < 4; ++m)
#pragma unroll
            for (int n = 0; n < 8; ++n) acc[m][n] = (f32x4){0.f, 0.f, 0.f, 0.f};

#define BADDR(i) ((((long)(ct0 + ((i) & 7)) * 8 + ((i) >> 3)) * 64 + lane) * 8)
        bf16x8 bring[4];
#pragma unroll
        for (int i = 0; i < 4; ++i) bring[i] = *(const bf16x8*)(whi + BADDR(i));

        bf16x8 ah[4];
#pragma unroll
        for (int i = 0; i < 64; ++i) {
            const int ks = i >> 3;
            const int n = i & 7;
            if (n == 0) {
#pragma unroll
                for (int m = 0; m < 4; ++m)
                    ah[m] = *(const bf16x8*)(ahi + A_SLOT(ks, m, lane));
            }
            bf16x8 bcur = bring[i & 3];
            if (i + 4 < 64) bring[i & 3] = *(const bf16x8*)(whi + BADDR(i + 4));
#pragma unroll
            for (int m = 0; m < 4; ++m)
                acc[m][n] = __builtin_amdgcn_mfma_f32_16x16x32_bf16(ah[m], bcur, acc[m][n], 0, 0, 0);
        }
#undef BADDR

        // np-grid dist + per-lane top-3 insert (no butterfly here)
#pragma unroll
        for (int n = 0; n < 8; ++n) {
            int code = (ct0 + n) * 16 + (lane & 15);
            float wq = wsq[code];
#pragma unroll
            for (int m = 0; m < 4; ++m) {
#pragma unroll
                for (int r = 0; r < 4; ++r) {
                    float tt = __fadd_rn(s1v[m][r], wq);
                    float dist = __fmaf_rn(-2.0f, acc[m][n][r], tt);
                    bool c1 = dist < e1d[m][r];
                    bool c2 = dist < e2d[m][r];
                    bool c3 = dist < e3d[m][r];
                    float n3 = c2 ? e2d[m][r] : (c3 ? dist : e3d[m][r]);
                    float n2 = c1 ? e1d[m][r] : (c2 ? dist : e2d[m][r]);
                    int   j2 = c1 ? e1i[m][r] : (c2 ? code : e2i[m][r]);
                    float n1 = c1 ? dist : e1d[m][r];
                    int   j1 = c1 ? code : e1i[m][r];
                    e3d[m][r] = n3; e2d[m][r] = n2; e2i[m][r] = j2;
                    e1d[m][r] = n1; e1i[m][r] = j1;
                }
            }
        }
    }

    // ---- single 16-lane butterfly with lex top-3 merge ----
#pragma unroll
    for (int step = 1; step < 16; step <<= 1) {
#pragma unroll
        for (int m = 0; m < 4; ++m) {
#pragma unroll
            for (int r = 0; r < 4; ++r) {
                float o1 = __shfl_xor(e1d[m][r], step);
                int   p1 = __shfl_xor(e1i[m][r], step);
                float o2 = __shfl_xor(e2d[m][r], step);
                int   p2 = __shfl_xor(e2i[m][r], step);
                float o3 = __shfl_xor(e3d[m][r], step);
                merge3(e1d[m][r], e1i[m][r], e2d[m][r], e2i[m][r], e3d[m][r],
                       o1, p1, o2, p2, o3);
            }
        }
    }

    if ((lane & 15) == 0) {
#pragma unroll
        for (int m = 0; m < 4; ++m) {
#pragma unroll
            for (int r = 0; r < 4; ++r) {
                int px = 16 * m + rbase + r;
                cd1[q][px] = e1d[m][r]; ci1[q][px] = e1i[m][r];
                cd2[q][px] = e2d[m][r]; ci2[q][px] = e2i[m][r];
                cd3[q][px] = e3d[m][r];
            }
        }
    }
    __syncthreads();

    // ---- cross-wave merge + classify: done / pair / full ----
    if (t < 64) {
        float d1 = cd1[0][t], d2 = cd2[0][t], d3 = cd3[0][t];
        int   i1 = ci1[0][t], i2 = ci2[0][t];
#pragma unroll
        for (int sq = 1; sq < 4; ++sq) {
            merge3(d1, i1, d2, i2, d3,
                   cd1[sq][t], ci1[sq][t], cd2[sq][t], ci2[sq][t], cd3[sq][t]);
        }
        const long n = px0 + t;
        idx[n] = i1;
        float m = d1 * 2.5e-6f;
        if (__fsub_rn(d3, d1) <= m) {
            int pos = atomicAdd(fullcnt, 1);
            if (pos < MAX_FLAGS) fullf[pos] = (int)n;
        } else if (__fsub_rn(d2, d1) <= m) {
            int pos = atomicAdd(paircnt, 1);
            if (pos < MAX_FLAGS) pairf[pos] = (int4){(int)n, i1, i2, 0};
        }
    }
}

// ---------- fallback VALU argmin (round-2 proven; emits full-flags only) ----------
__global__ __launch_bounds__(256, 2)
void k_argmin_valu(const float* __restrict__ x, const float* __restrict__ w,
                   const float* __restrict__ wsq, const float* __restrict__ xsq,
                   int* __restrict__ idx, int* __restrict__ fullf, int* __restrict__ fullcnt) {
    __shared__ float xs[64 * 257];
    __shared__ float sd1[4][64];
    __shared__ float sd2[4][64];
    __shared__ int   si1[4][64];

    const int t = threadIdx.x;
    const int p = t & 63;
    const int q = t >> 6;
    const long n0 = (long)blockIdx.x * 64;
    const int b = (int)(n0 >> 12);
    const int hw0 = (int)(n0 & 4095);
    const float* xb = x + (long)b * DIM * HW + hw0;

    for (int i = 0; i < 64; ++i) {
        int c = q * 64 + i;
        xs[p * 257 + c] = xb[(long)c * HW + p];
    }
    __syncthreads();

    const float* xrow = xs + p * 257;
    const float s1 = xsq[n0 + p];
    float d1 = INFINITY, d2 = INFINITY;
    int i1 = 0;
    const int kbase = q * 256;
    const float* wq = w + (long)kbase * DIM;
    const float* wsq_q = wsq + kbase;

    for (int kc = 0; kc < 256; kc += 8) {
        float acc[8] = {0.f, 0.f, 0.f, 0.f, 0.f, 0.f, 0.f, 0.f};
        const float* w0 = wq + (long)kc * DIM;
#pragma unroll 2
        for (int d = 0; d < DIM; d += 4) {
            float x0 = xrow[d + 0];
            float x1 = xrow[d + 1];
            float x2 = xrow[d + 2];
            float x3 = xrow[d + 3];
#pragma unroll
            for (int j = 0; j < 8; ++j) {
                const float4 wv = *reinterpret_cast<const float4*>(w0 + j * DIM + d);
                acc[j] = __fmaf_rn(x0, wv.x, acc[j]);
                acc[j] = __fmaf_rn(x1, wv.y, acc[j]);
                acc[j] = __fmaf_rn(x2, wv.z, acc[j]);
                acc[j] = __fmaf_rn(x3, wv.w, acc[j]);
            }
        }
#pragma unroll
        for (int j = 0; j < 8; ++j) {
            float tk = __fadd_rn(s1, wsq_q[kc + j]);
            float dist = __fsub_rn(tk, __fmul_rn(2.0f, acc[j]));
            if (dist < d1) { d2 = d1; d1 = dist; i1 = kbase + kc + j; }
            else if (dist < d2) { d2 = dist; }
        }
    }

    sd1[q][p] = d1; sd2[q][p] = d2; si1[q][p] = i1;
    __syncthreads();
    if (q == 0) {
        float bd1 = sd1[0][p], bd2 = sd2[0][p];
        int bi = si1[0][p];
#pragma unroll
        for (int j = 1; j < 4; ++j) {
            float a1 = sd1[j][p], a2 = sd2[j][p];
            int ai = si1[j][p];
            if (a1 < bd1) { bd2 = fminf(bd1, a2); bd1 = a1; bi = ai; }
            else { bd2 = fminf(bd2, fminf(a1, a2)); }
        }
        const long n = n0 + p;
        idx[n] = bi;
        if (__fsub_rn(bd2, bd1) <= bd1 * 6.0e-7f) {
            int pos = atomicAdd(fullcnt, 1);
            if (pos < MAX_FLAGS) fullf[pos] = (int)n;
        }
    }
}

// ---------------------------------------------------------------------------
// pair refine (proven rounds 9-13): one wave per pixel, exact f64 dots for
// the two candidates, butterfly sum, np-grid dist, lex winner.
// ---------------------------------------------------------------------------
__global__ __launch_bounds__(256)
void k_refine_pair(const float* __restrict__ x, const float* __restrict__ w,
                   const float* __restrict__ wsq, const float* __restrict__ xsq,
                   const int4* __restrict__ pairf, const int* __restrict__ paircnt,
                   int* __restrict__ idx) {
    int np = *paircnt;
    if (np > MAX_FLAGS) np = MAX_FLAGS;
    const int lane = threadIdx.x & 63;
    const int wv = threadIdx.x >> 6;
    for (int fi = blockIdx.x * 4 + wv; fi < np; fi += gridDim.x * 4) {
        int4 f = pairf[fi];
        int n = f.x, c1 = f.y, c2 = f.z;
        int b = n >> 12, hw = n & 4095;
        const float* xp = x + (long)b * (DIM * HW) + hw;
        double xd0 = (double)xp[(long)(lane * 4 + 0) * HW];
        double xd1 = (double)xp[(long)(lane * 4 + 1) * HW];
        double xd2 = (double)xp[(long)(lane * 4 + 2) * HW];
        double xd3 = (double)xp[(long)(lane * 4 + 3) * HW];
        const float4 w1 = *reinterpret_cast<const float4*>(w + (long)c1 * DIM + lane * 4);
        const float4 w2 = *reinterpret_cast<const float4*>(w + (long)c2 * DIM + lane * 4);
        double s1 = fma((double)w1.x, xd0, fma((double)w1.y, xd1,
                    fma((double)w1.z, xd2, (double)w1.w * xd3)));
        double s2 = fma((double)w2.x, xd0, fma((double)w2.y, xd1,
                    fma((double)w2.z, xd2, (double)w2.w * xd3)));
#pragma unroll
        for (int st = 1; st < 64; st <<= 1) {
            s1 += __shfl_xor(s1, st);
            s2 += __shfl_xor(s2, st);
        }
        if (lane == 0) {
            float xq = xsq[n];
            float dk1 = __fsub_rn(__fadd_rn(xq, wsq[c1]), __fmul_rn(2.0f, (float)s1));
            float dk2 = __fsub_rn(__fadd_rn(xq, wsq[c2]), __fmul_rn(2.0f, (float)s2));
            bool take2 = (dk2 < dk1) || (dk2 == dk1 && c2 < c1);
            idx[n] = take2 ? c2 : c1;
        }
    }
}

// ---------------------------------------------------------------------------
// full refine (proven rounds 9-13): 8 px x 1024 codes per block
// ---------------------------------------------------------------------------
__global__ __launch_bounds__(1024)
void k_refine_full(const float* __restrict__ x, const float* __restrict__ wtr,
                   const float* __restrict__ wsq, const float* __restrict__ xsq,
                   const int* __restrict__ fullf, const int* __restrict__ fullcnt,
                   int* __restrict__ idx) {
    __shared__ float xsf[DIM][8];       // 8KB
    __shared__ int   np_s[8];
    __shared__ float s1_s[8];
    __shared__ float wd[16][8];
    __shared__ int   wi[16][8];

    int nf = *fullcnt;
    if (nf > MAX_FLAGS) nf = MAX_FLAGS;
    const int t = threadIdx.x;
    const int lane = t & 63;
    const int wid = t >> 6;

    for (int base = blockIdx.x * 8; base < nf; base += gridDim.x * 8) {
        __syncthreads();
        if (t < 8) {
            int fi = base + t;
            int n = fullf[fi < nf ? fi : (nf - 1)];
            np_s[t] = n;
            s1_s[t] = xsq[n];
        }
        __syncthreads();
#pragma unroll
        for (int e = t; e < 2048; e += 1024) {
            int p = e & 7, d = e >> 3;
            int n = np_s[p];
            xsf[d][p] = x[(long)(n >> 12) * (DIM * HW) + (long)d * HW + (n & 4095)];
        }
        __syncthreads();

        const float wq = wsq[t];
        double acc[8] = {0.0, 0.0, 0.0, 0.0, 0.0, 0.0, 0.0, 0.0};
#pragma unroll 4
        for (int d = 0; d < DIM; ++d) {
            double wk = (double)wtr[(long)d * NUM_K + t];
#pragma unroll
            for (int p = 0; p < 8; ++p) acc[p] = fma(wk, (double)xsf[d][p], acc[p]);
        }

        float dkv[8];
        int   kiv[8];
#pragma unroll
        for (int p = 0; p < 8; ++p) {
            dkv[p] = __fsub_rn(__fadd_rn(s1_s[p], wq), __fmul_rn(2.0f, (float)acc[p]));
            kiv[p] = t;
        }
#pragma unroll
        for (int step = 1; step < 64; step <<= 1) {
#pragma unroll
            for (int p = 0; p < 8; ++p) {
                float od = __shfl_xor(dkv[p], step);
                int   oi = __shfl_xor(kiv[p], step);
                if (od < dkv[p] || (od == dkv[p] && oi < kiv[p])) { dkv[p] = od; kiv[p] = oi; }
            }
        }
        if (lane == 0) {
#pragma unroll
            for (int p = 0; p < 8; ++p) { wd[wid][p] = dkv[p]; wi[wid][p] = kiv[p]; }
        }
        __syncthreads();
        if (t < 8) {
            float bd = wd[0][t];
            int   bi = wi[0][t];
#pragma unroll
            for (int sq = 1; sq < 16; ++sq) {
                float ad = wd[sq][t];
                int   ai = wi[sq][t];
                if (ad < bd || (ad == bd && ai < bi)) { bd = ad; bi = ai; }
            }
            if (base + t < nf) idx[np_s[t]] = bi;
        }
    }
}

// ---------- gather + straight-through + loss ----------
__global__ __launch_bounds__(256, 2)
void k_quant(const float* __restrict__ x, const float* __restrict__ w,
             const int* __restrict__ idx, float* __restrict__ qout,
             float* __restrict__ iout, float* __restrict__ loss) {
    __shared__ float wrow[64 * 257];
    __shared__ int lidx[64];
    __shared__ float part[4];
    const int t = threadIdx.x;
    const long n0 = (long)blockIdx.x * 64;
    const int b = (int)(n0 >> 12), hw0 = (int)(n0 & 4095);

    if (t < 64) lidx[t] = idx[n0 + t];
    __syncthreads();
    for (int i = 0; i < 64; ++i) {
        wrow[i * 257 + t] = w[(long)lidx[i] * DIM + t];
    }
    if (t < 64) iout[n0 + t] = (float)lidx[t];
    __syncthreads();

    const int p = t & 63, cg = t >> 6;
    const float* xb = x + (long)b * DIM * HW + hw0;
    float* qb = qout + (long)b * DIM * HW + hw0;
    float lsum = 0.f;
    for (int i = 0; i < 64; ++i) {
        int c = cg * 64 + i;
        float qv = wrow[p * 257 + c];
        long off = (long)c * HW + p;
        float xv = xb[off];
        float diff = __fsub_rn(qv, xv);
        qb[off] = __fadd_rn(xv, diff);
        lsum = __fmaf_rn(diff, diff, lsum);
    }
#pragma unroll
    for (int off = 32; off; off >>= 1) lsum += __shfl_down(lsum, off);
    if ((t & 63) == 0) part[t >> 6] = lsum;
    __syncthreads();
    if (t == 0) {
        float tot = (part[0] + part[1]) + (part[2] + part[3]);
        atomicAdd(loss, tot * (1.25f / 16777216.f));
    }
}

extern "C" void kernel_launch(void* const* d_in, const int* in_sizes, int n_in,
                              void* d_out, int out_size, void* d_ws, size_t ws_size,
                              hipStream_t stream) {
    const float* x = (const float*)d_in[0];
    const float* w = (const float*)d_in[1];

    float* qout = (float*)d_out;
    float* iout = qout + QELEMS;
    float* loss = iout + NPIX;

    char* wp = (char*)d_ws;
    int*   idx     = (int*)wp;      wp += (size_t)NPIX * 4;           // 256KB
    float* wsq     = (float*)wp;    wp += (size_t)NUM_K * 4;          // 4KB
    float* xsq     = (float*)wp;    wp += (size_t)NPIX * 4;           // 256KB
    int4*  pairf   = (int4*)wp;     wp += (size_t)MAX_FLAGS * 16;     // 256KB
    int*   paircnt = (int*)wp;      wp += 256;
    int*   fullf   = (int*)wp;      wp += (size_t)MAX_FLAGS * 4;      // 64KB
    int*   fullcnt = (int*)wp;      wp += 256;
    float* wtr     = (float*)wp;    wp += (size_t)NUM_K * DIM * 4;    // 1MB
    short* whi     = (short*)wp;    wp += (size_t)NUM_K * DIM * 2;    // 512KB
    size_t need = (size_t)(wp - (char*)d_ws);

    k_prep<<<260, 256, 0, stream>>>(w, wsq, wtr, whi, loss, paircnt, fullcnt);

    if (ws_size >= need) {
        k_argmin_mfma<<<1024, 256, 0, stream>>>(x, whi, wsq, xsq, idx,
                                                pairf, paircnt, fullf, fullcnt);
        k_refine_pair<<<2048, 256, 0, stream>>>(x, w, wsq, xsq, pairf, paircnt, idx);
    } else {
        k_xsq<<<NPIX / 256, 256, 0, stream>>>(x, xsq);
        k_argmin_valu<<<NPIX / 64, 256, 0, stream>>>(x, w, wsq, xsq, idx, fullf, fullcnt);
    }
    k_refine_full<<<512, 1024, 0, stream>>>(x, wtr, wsq, xsq, fullf, fullcnt, idx);
    k_quant<<<NPIX / 64, 256, 0, stream>>>(x, w, idx, qout, iout, loss);
}

// Round 15
// 224.039 us; speedup vs baseline: 1.8693x; 1.8693x over previous
//
#include <hip/hip_runtime.h>
#include <math.h>

#define NUM_K 1024
#define DIM 256
#define HW 4096          // 64*64
#define NPIX 65536       // 16*4096
#define QELEMS 16777216  // 16*256*4096
#define MAX_FLAGS 16384

typedef short bf16x8 __attribute__((ext_vector_type(8)));
typedef float f32x4 __attribute__((ext_vector_type(4)));

__device__ __forceinline__ unsigned short f32_to_bf16_rne(float f) {
    unsigned int u = __float_as_uint(f);
    unsigned int r = u + 0x7FFFu + ((u >> 16) & 1u);
    return (unsigned short)(r >> 16);
}

// merge two lex-sorted top-3 states (proven rounds 9-13, absmax 0)
__device__ __forceinline__ void merge3(float& a1d, int& a1i, float& a2d, int& a2i, float& a3d,
                                       float b1d, int b1i, float b2d, int b2i, float b3d) {
    bool bf = (b1d < a1d) || (b1d == a1d && b1i < a1i);
    float r1d = bf ? b1d : a1d; int r1i = bf ? b1i : a1i;
    float n2d = bf ? b2d : a2d; int n2i = bf ? b2i : a2i;
    float o1d = bf ? a1d : b1d; int o1i = bf ? a1i : b1i;
    bool k2 = (n2d < o1d) || (n2d == o1d && n2i < o1i);
    float r2d = k2 ? n2d : o1d; int r2i = k2 ? n2i : o1i;
    float sm3 = bf ? b3d : a3d;
    float o2d = bf ? a2d : b2d;
    float r3d = k2 ? fminf(sm3, o1d) : fminf(n2d, o2d);
    a1d = r1d; a1i = r1i; a2d = r2d; a2i = r2i; a3d = r3d;
}

// ---------------------------------------------------------------------------
// numpy-replicated f32 sum of squares (pairwise SIMD tree, proven rounds 2-14)
// ---------------------------------------------------------------------------
__device__ __forceinline__ float np_sumsq_256(const float* __restrict__ p, long stride) {
    float blk0 = 0.f, blk1 = 0.f;
#pragma unroll
    for (int h = 0; h < 2; ++h) {
        const float* base = p + (long)h * 128 * stride;
        float s[16];
#pragma unroll
        for (int L = 0; L < 16; ++L) {
            float a0 = base[(long)(L)       * stride]; a0 = __fmul_rn(a0, a0);
            float a1 = base[(long)(16 + L)  * stride]; a1 = __fmul_rn(a1, a1);
            float a2 = base[(long)(32 + L)  * stride]; a2 = __fmul_rn(a2, a2);
            float a3 = base[(long)(48 + L)  * stride]; a3 = __fmul_rn(a3, a3);
            float a4 = base[(long)(64 + L)  * stride]; a4 = __fmul_rn(a4, a4);
            float a5 = base[(long)(80 + L)  * stride]; a5 = __fmul_rn(a5, a5);
            float a6 = base[(long)(96 + L)  * stride]; a6 = __fmul_rn(a6, a6);
            float a7 = base[(long)(112 + L) * stride]; a7 = __fmul_rn(a7, a7);
            float t1 = __fadd_rn(a0, a1);
            float t2 = __fadd_rn(a2, a3);
            float t3 = __fadd_rn(a4, a5);
            float t4 = __fadd_rn(a6, a7);
            s[L] = __fadd_rn(__fadd_rn(t1, t2), __fadd_rn(t3, t4));
        }
        float c0 = __fadd_rn(s[0], s[8]);
        float c1 = __fadd_rn(s[1], s[9]);
        float c2 = __fadd_rn(s[2], s[10]);
        float c3 = __fadd_rn(s[3], s[11]);
        float c4 = __fadd_rn(s[4], s[12]);
        float c5 = __fadd_rn(s[5], s[13]);
        float c6 = __fadd_rn(s[6], s[14]);
        float c7 = __fadd_rn(s[7], s[15]);
        float d0 = __fadd_rn(c0, c4);
        float d1 = __fadd_rn(c1, c5);
        float d2 = __fadd_rn(c2, c6);
        float d3 = __fadd_rn(c3, c7);
        float e0 = __fadd_rn(d0, d2);
        float e1 = __fadd_rn(d1, d3);
        float r  = __fadd_rn(e0, e1);
        if (h == 0) blk0 = r; else blk1 = r;
    }
    return __fadd_rn(blk0, blk1);
}

// ---------------------------------------------------------------------------
// fused prep: blocks 0..127 wfrag, 128..255 wtrans, 256..259 wsq (+zero init)
// (round-14 lever #2, kept — orthogonal to the spill)
// ---------------------------------------------------------------------------
__global__ __launch_bounds__(256)
void k_prep(const float* __restrict__ w, float* __restrict__ wsq,
            float* __restrict__ wtr, short* __restrict__ whi,
            float* __restrict__ loss, int* __restrict__ paircnt, int* __restrict__ fullcnt) {
    const int bk = blockIdx.x;
    const int t = threadIdx.x;
    if (bk < 128) {
        int id = bk * 256 + t;                 // 32768 = 1024 codes * 32 chunks
        int code = id >> 5;
        int c = id & 31;
        const float* src = w + (long)code * DIM + c * 8;
        bf16x8 vh;
#pragma unroll
        for (int j = 0; j < 8; ++j) vh[j] = (short)f32_to_bf16_rne(src[j]);
        int fl = ((c & 3) << 4) | (code & 15);
        long addr = ((((long)(code >> 4) * 8 + (c >> 2)) * 64 + fl) * 8);
        *(bf16x8*)(whi + addr) = vh;
    } else if (bk < 256) {
        int d0 = (bk - 128) * 2;
#pragma unroll
        for (int dd = 0; dd < 2; ++dd) {
            int d = d0 + dd;
#pragma unroll
            for (int kk = 0; kk < 4; ++kk) {
                int k = kk * 256 + t;
                wtr[(long)d * NUM_K + k] = w[(long)k * DIM + d];
            }
        }
    } else {
        int k = (bk - 256) * 256 + t;
        wsq[k] = np_sumsq_256(w + (long)k * DIM, 1);
        if (bk == 256 && t == 0) { *loss = 0.f; *paircnt = 0; *fullcnt = 0; }
    }
}

// fallback-only (main path fuses xsq into argmin)
__global__ __launch_bounds__(256) void k_xsq(const float* __restrict__ x, float* __restrict__ xsq) {
    int n = blockIdx.x * 256 + threadIdx.x;
    int b = n >> 12, hw = n & 4095;
    xsq[n] = np_sumsq_256(x + (long)b * DIM * HW + hw, HW);
}

// ---------------------------------------------------------------------------
// MFMA argmin v15 = round-13's PROVEN kernel verbatim (125us, VGPR 128,
// no spill). Round-14 lesson (spill trap #3): epilogue state must NOT live
// across a sweep's MFMA loop — the per-sweep butterfly is register
// COMPRESSION (80 regs -> 20 LDS floats), not overhead. Do not hoist it.
// ---------------------------------------------------------------------------
#define A_SLOT(ks,m,fl) ((((ks)*4+(m))*64+(fl))*8)

__global__ __launch_bounds__(256, 2)
void k_argmin_mfma(const float* __restrict__ x,
                   const short* __restrict__ whi,
                   const float* __restrict__ wsq, float* __restrict__ xsq,
                   int* __restrict__ idx,
                   int4* __restrict__ pairf, int* __restrict__ paircnt,
                   int* __restrict__ fullf, int* __restrict__ fullcnt) {
    __shared__ short ahi[8 * 4 * 64 * 8];      // 32KB [ks][m][fl][j]
    __shared__ float xpart[4 * 16 * 64];       // 16KB [q][L][px] numpy-tree partials
    __shared__ float xsq_s[64];
    __shared__ float cd1[4][64], cd2[4][64], cd3[4][64];
    __shared__ int   ci1[4][64], ci2[4][64];

    const int t = threadIdx.x;
    const int lane = t & 63;
    const int q = t >> 6;
    const int tile = blockIdx.x;               // 1024 tiles of 64 px
    const int b = tile >> 6;
    const int hw0 = (tile & 63) * 64;
    const long px0 = (long)tile * 64;
    const float* xb = x + (long)b * (DIM * HW) + hw0 + lane;

    // ---- stage A (once) + numpy-tree square partials (proven rounds 12-13) ----
    {
        float tmp[16], part[16];
#pragma unroll
        for (int i = 0; i < 8; ++i) {
            int c = q * 8 + i;                 // d-chunk: d = c*8 + jj
            float v[8];
#pragma unroll
            for (int jj = 0; jj < 8; ++jj) v[jj] = xb[(long)(c * 8 + jj) * HW];
            bf16x8 vh;
#pragma unroll
            for (int jj = 0; jj < 8; ++jj) vh[jj] = (short)f32_to_bf16_rne(v[jj]);
            int slot = A_SLOT(c >> 2, lane >> 4, ((c & 3) << 4) | (lane & 15));
            *(bf16x8*)(ahi + slot) = vh;
            const int kp = i >> 1;
#pragma unroll
            for (int jj = 0; jj < 8; ++jj) {
                int L = ((i & 1) << 3) | jj;
                float a = __fmul_rn(v[jj], v[jj]);
                if (kp == 0) tmp[L] = a;
                else if (kp == 1) part[L] = __fadd_rn(tmp[L], a);
                else if (kp == 2) tmp[L] = a;
                else part[L] = __fadd_rn(part[L], __fadd_rn(tmp[L], a));
            }
        }
#pragma unroll
        for (int L = 0; L < 16; ++L) xpart[(q * 16 + L) * 64 + lane] = part[L];
    }
    __syncthreads();

    // ---- finisher: complete np_sumsq per pixel (t<64), LDS + global ----
    if (t < 64) {
        float blk[2];
#pragma unroll
        for (int h = 0; h < 2; ++h) {
            float s[16];
#pragma unroll
            for (int L = 0; L < 16; ++L)
                s[L] = __fadd_rn(xpart[((2 * h) * 16 + L) * 64 + t],
                                 xpart[((2 * h + 1) * 16 + L) * 64 + t]);
            float c0 = __fadd_rn(s[0], s[8]);
            float c1 = __fadd_rn(s[1], s[9]);
            float c2 = __fadd_rn(s[2], s[10]);
            float c3 = __fadd_rn(s[3], s[11]);
            float c4 = __fadd_rn(s[4], s[12]);
            float c5 = __fadd_rn(s[5], s[13]);
            float c6 = __fadd_rn(s[6], s[14]);
            float c7 = __fadd_rn(s[7], s[15]);
            float d0 = __fadd_rn(c0, c4);
            float d1 = __fadd_rn(c1, c5);
            float d2 = __fadd_rn(c2, c6);
            float d3 = __fadd_rn(c3, c7);
            float e0 = __fadd_rn(d0, d2);
            float e1 = __fadd_rn(d1, d3);
            blk[h] = __fadd_rn(e0, e1);
        }
        float v = __fadd_rn(blk[0], blk[1]);
        xsq_s[t] = v;
        xsq[px0 + t] = v;                      // for the exact-refine kernels
    }
    __syncthreads();

    // ---- two K-sweeps; per-lane top-3 each, butterfly + LDS merge PER SWEEP ----
#pragma unroll
    for (int s = 0; s < 2; ++s) {
        const int ct0 = s * 32 + q * 8;
        f32x4 acc[4][8];
#pragma unroll
        for (int m = 0; m < 4; ++m)
#pragma unroll
            for (int n = 0; n < 8; ++n) acc[m][n] = (f32x4){0.f, 0.f, 0.f, 0.f};

#define BADDR(i) ((((long)(ct0 + ((i) & 7)) * 8 + ((i) >> 3)) * 64 + lane) * 8)
        bf16x8 bring[4];
#pragma unroll
        for (int i = 0; i < 4; ++i) bring[i] = *(const bf16x8*)(whi + BADDR(i));

        bf16x8 ah[4];
#pragma unroll
        for (int i = 0; i < 64; ++i) {
            const int ks = i >> 3;
            const int n = i & 7;
            if (n == 0) {
#pragma unroll
                for (int m = 0; m < 4; ++m)
                    ah[m] = *(const bf16x8*)(ahi + A_SLOT(ks, m, lane));
            }
            bf16x8 bcur = bring[i & 3];
            if (i + 4 < 64) bring[i & 3] = *(const bf16x8*)(whi + BADDR(i + 4));
#pragma unroll
            for (int m = 0; m < 4; ++m)
                acc[m][n] = __builtin_amdgcn_mfma_f32_16x16x32_bf16(ah[m], bcur, acc[m][n], 0, 0, 0);
        }
#undef BADDR

        // epilogue: np-grid dist + per-lane top-3 (proven rounds 9-13)
        const int rbase = (lane >> 4) * 4;
        float s1v[4][4];
#pragma unroll
        for (int m = 0; m < 4; ++m)
#pragma unroll
            for (int r = 0; r < 4; ++r) s1v[m][r] = xsq_s[16 * m + rbase + r];

        float e1d[4][4], e2d[4][4], e3d[4][4];
        int   e1i[4][4], e2i[4][4];
#pragma unroll
        for (int m = 0; m < 4; ++m)
#pragma unroll
            for (int r = 0; r < 4; ++r) {
                e1d[m][r] = INFINITY; e2d[m][r] = INFINITY; e3d[m][r] = INFINITY;
                e1i[m][r] = 0; e2i[m][r] = 0;
            }

#pragma unroll
        for (int n = 0; n < 8; ++n) {
            int code = (ct0 + n) * 16 + (lane & 15);
            float wq = wsq[code];
#pragma unroll
            for (int m = 0; m < 4; ++m) {
#pragma unroll
                for (int r = 0; r < 4; ++r) {
                    float tt = __fadd_rn(s1v[m][r], wq);
                    float dist = __fmaf_rn(-2.0f, acc[m][n][r], tt);
                    bool c1 = dist < e1d[m][r];
                    bool c2 = dist < e2d[m][r];
                    bool c3 = dist < e3d[m][r];
                    float n3 = c2 ? e2d[m][r] : (c3 ? dist : e3d[m][r]);
                    float n2 = c1 ? e1d[m][r] : (c2 ? dist : e2d[m][r]);
                    int   j2 = c1 ? e1i[m][r] : (c2 ? code : e2i[m][r]);
                    float n1 = c1 ? dist : e1d[m][r];
                    int   j1 = c1 ? code : e1i[m][r];
                    e3d[m][r] = n3; e2d[m][r] = n2; e2i[m][r] = j2;
                    e1d[m][r] = n1; e1i[m][r] = j1;
                }
            }
        }

#pragma unroll
        for (int step = 1; step < 16; step <<= 1) {
#pragma unroll
            for (int m = 0; m < 4; ++m) {
#pragma unroll
                for (int r = 0; r < 4; ++r) {
                    float o1 = __shfl_xor(e1d[m][r], step);
                    int   p1 = __shfl_xor(e1i[m][r], step);
                    float o2 = __shfl_xor(e2d[m][r], step);
                    int   p2 = __shfl_xor(e2i[m][r], step);
                    float o3 = __shfl_xor(e3d[m][r], step);
                    merge3(e1d[m][r], e1i[m][r], e2d[m][r], e2i[m][r], e3d[m][r],
                           o1, p1, o2, p2, o3);
                }
            }
        }

        if ((lane & 15) == 0) {
#pragma unroll
            for (int m = 0; m < 4; ++m) {
#pragma unroll
                for (int r = 0; r < 4; ++r) {
                    int px = 16 * m + rbase + r;
                    if (s == 0) {
                        cd1[q][px] = e1d[m][r]; ci1[q][px] = e1i[m][r];
                        cd2[q][px] = e2d[m][r]; ci2[q][px] = e2i[m][r];
                        cd3[q][px] = e3d[m][r];
                    } else {
                        float a1 = cd1[q][px], a2 = cd2[q][px], a3 = cd3[q][px];
                        int   ai = ci1[q][px], aj = ci2[q][px];
                        merge3(a1, ai, a2, aj, a3,
                               e1d[m][r], e1i[m][r], e2d[m][r], e2i[m][r], e3d[m][r]);
                        cd1[q][px] = a1; ci1[q][px] = ai;
                        cd2[q][px] = a2; ci2[q][px] = aj;
                        cd3[q][px] = a3;
                    }
                }
            }
        }
    }
    __syncthreads();

    // ---- cross-wave merge + classify: done / pair / full ----
    if (t < 64) {
        float d1 = cd1[0][t], d2 = cd2[0][t], d3 = cd3[0][t];
        int   i1 = ci1[0][t], i2 = ci2[0][t];
#pragma unroll
        for (int sq = 1; sq < 4; ++sq) {
            merge3(d1, i1, d2, i2, d3,
                   cd1[sq][t], ci1[sq][t], cd2[sq][t], ci2[sq][t], cd3[sq][t]);
        }
        const long n = px0 + t;
        idx[n] = i1;
        float m = d1 * 2.5e-6f;
        if (__fsub_rn(d3, d1) <= m) {
            int pos = atomicAdd(fullcnt, 1);
            if (pos < MAX_FLAGS) fullf[pos] = (int)n;
        } else if (__fsub_rn(d2, d1) <= m) {
            int pos = atomicAdd(paircnt, 1);
            if (pos < MAX_FLAGS) pairf[pos] = (int4){(int)n, i1, i2, 0};
        }
    }
}

// ---------- fallback VALU argmin (round-2 proven; emits full-flags only) ----------
__global__ __launch_bounds__(256, 2)
void k_argmin_valu(const float* __restrict__ x, const float* __restrict__ w,
                   const float* __restrict__ wsq, const float* __restrict__ xsq,
                   int* __restrict__ idx, int* __restrict__ fullf, int* __restrict__ fullcnt) {
    __shared__ float xs[64 * 257];
    __shared__ float sd1[4][64];
    __shared__ float sd2[4][64];
    __shared__ int   si1[4][64];

    const int t = threadIdx.x;
    const int p = t & 63;
    const int q = t >> 6;
    const long n0 = (long)blockIdx.x * 64;
    const int b = (int)(n0 >> 12);
    const int hw0 = (int)(n0 & 4095);
    const float* xb = x + (long)b * DIM * HW + hw0;

    for (int i = 0; i < 64; ++i) {
        int c = q * 64 + i;
        xs[p * 257 + c] = xb[(long)c * HW + p];
    }
    __syncthreads();

    const float* xrow = xs + p * 257;
    const float s1 = xsq[n0 + p];
    float d1 = INFINITY, d2 = INFINITY;
    int i1 = 0;
    const int kbase = q * 256;
    const float* wq = w + (long)kbase * DIM;
    const float* wsq_q = wsq + kbase;

    for (int kc = 0; kc < 256; kc += 8) {
        float acc[8] = {0.f, 0.f, 0.f, 0.f, 0.f, 0.f, 0.f, 0.f};
        const float* w0 = wq + (long)kc * DIM;
#pragma unroll 2
        for (int d = 0; d < DIM; d += 4) {
            float x0 = xrow[d + 0];
            float x1 = xrow[d + 1];
            float x2 = xrow[d + 2];
            float x3 = xrow[d + 3];
#pragma unroll
            for (int j = 0; j < 8; ++j) {
                const float4 wv = *reinterpret_cast<const float4*>(w0 + j * DIM + d);
                acc[j] = __fmaf_rn(x0, wv.x, acc[j]);
                acc[j] = __fmaf_rn(x1, wv.y, acc[j]);
                acc[j] = __fmaf_rn(x2, wv.z, acc[j]);
                acc[j] = __fmaf_rn(x3, wv.w, acc[j]);
            }
        }
#pragma unroll
        for (int j = 0; j < 8; ++j) {
            float tk = __fadd_rn(s1, wsq_q[kc + j]);
            float dist = __fsub_rn(tk, __fmul_rn(2.0f, acc[j]));
            if (dist < d1) { d2 = d1; d1 = dist; i1 = kbase + kc + j; }
            else if (dist < d2) { d2 = dist; }
        }
    }

    sd1[q][p] = d1; sd2[q][p] = d2; si1[q][p] = i1;
    __syncthreads();
    if (q == 0) {
        float bd1 = sd1[0][p], bd2 = sd2[0][p];
        int bi = si1[0][p];
#pragma unroll
        for (int j = 1; j < 4; ++j) {
            float a1 = sd1[j][p], a2 = sd2[j][p];
            int ai = si1[j][p];
            if (a1 < bd1) { bd2 = fminf(bd1, a2); bd1 = a1; bi = ai; }
            else { bd2 = fminf(bd2, fminf(a1, a2)); }
        }
        const long n = n0 + p;
        idx[n] = bi;
        if (__fsub_rn(bd2, bd1) <= bd1 * 6.0e-7f) {
            int pos = atomicAdd(fullcnt, 1);
            if (pos < MAX_FLAGS) fullf[pos] = (int)n;
        }
    }
}

// ---------------------------------------------------------------------------
// pair refine (proven rounds 9-13): one wave per pixel, exact f64 dots for
// the two candidates, butterfly sum, np-grid dist, lex winner.
// ---------------------------------------------------------------------------
__global__ __launch_bounds__(256)
void k_refine_pair(const float* __restrict__ x, const float* __restrict__ w,
                   const float* __restrict__ wsq, const float* __restrict__ xsq,
                   const int4* __restrict__ pairf, const int* __restrict__ paircnt,
                   int* __restrict__ idx) {
    int np = *paircnt;
    if (np > MAX_FLAGS) np = MAX_FLAGS;
    const int lane = threadIdx.x & 63;
    const int wv = threadIdx.x >> 6;
    for (int fi = blockIdx.x * 4 + wv; fi < np; fi += gridDim.x * 4) {
        int4 f = pairf[fi];
        int n = f.x, c1 = f.y, c2 = f.z;
        int b = n >> 12, hw = n & 4095;
        const float* xp = x + (long)b * (DIM * HW) + hw;
        double xd0 = (double)xp[(long)(lane * 4 + 0) * HW];
        double xd1 = (double)xp[(long)(lane * 4 + 1) * HW];
        double xd2 = (double)xp[(long)(lane * 4 + 2) * HW];
        double xd3 = (double)xp[(long)(lane * 4 + 3) * HW];
        const float4 w1 = *reinterpret_cast<const float4*>(w + (long)c1 * DIM + lane * 4);
        const float4 w2 = *reinterpret_cast<const float4*>(w + (long)c2 * DIM + lane * 4);
        double s1 = fma((double)w1.x, xd0, fma((double)w1.y, xd1,
                    fma((double)w1.z, xd2, (double)w1.w * xd3)));
        double s2 = fma((double)w2.x, xd0, fma((double)w2.y, xd1,
                    fma((double)w2.z, xd2, (double)w2.w * xd3)));
#pragma unroll
        for (int st = 1; st < 64; st <<= 1) {
            s1 += __shfl_xor(s1, st);
            s2 += __shfl_xor(s2, st);
        }
        if (lane == 0) {
            float xq = xsq[n];
            float dk1 = __fsub_rn(__fadd_rn(xq, wsq[c1]), __fmul_rn(2.0f, (float)s1));
            float dk2 = __fsub_rn(__fadd_rn(xq, wsq[c2]), __fmul_rn(2.0f, (float)s2));
            bool take2 = (dk2 < dk1) || (dk2 == dk1 && c2 < c1);
            idx[n] = take2 ? c2 : c1;
        }
    }
}

// ---------------------------------------------------------------------------
// full refine (proven rounds 9-13): 8 px x 1024 codes per block
// ---------------------------------------------------------------------------
__global__ __launch_bounds__(1024)
void k_refine_full(const float* __restrict__ x, const float* __restrict__ wtr,
                   const float* __restrict__ wsq, const float* __restrict__ xsq,
                   const int* __restrict__ fullf, const int* __restrict__ fullcnt,
                   int* __restrict__ idx) {
    __shared__ float xsf[DIM][8];       // 8KB
    __shared__ int   np_s[8];
    __shared__ float s1_s[8];
    __shared__ float wd[16][8];
    __shared__ int   wi[16][8];

    int nf = *fullcnt;
    if (nf > MAX_FLAGS) nf = MAX_FLAGS;
    const int t = threadIdx.x;
    const int lane = t & 63;
    const int wid = t >> 6;

    for (int base = blockIdx.x * 8; base < nf; base += gridDim.x * 8) {
        __syncthreads();
        if (t < 8) {
            int fi = base + t;
            int n = fullf[fi < nf ? fi : (nf - 1)];
            np_s[t] = n;
            s1_s[t] = xsq[n];
        }
        __syncthreads();
#pragma unroll
        for (int e = t; e < 2048; e += 1024) {
            int p = e & 7, d = e >> 3;
            int n = np_s[p];
            xsf[d][p] = x[(long)(n >> 12) * (DIM * HW) + (long)d * HW + (n & 4095)];
        }
        __syncthreads();

        const float wq = wsq[t];
        double acc[8] = {0.0, 0.0, 0.0, 0.0, 0.0, 0.0, 0.0, 0.0};
#pragma unroll 4
        for (int d = 0; d < DIM; ++d) {
            double wk = (double)wtr[(long)d * NUM_K + t];
#pragma unroll
            for (int p = 0; p < 8; ++p) acc[p] = fma(wk, (double)xsf[d][p], acc[p]);
        }

        float dkv[8];
        int   kiv[8];
#pragma unroll
        for (int p = 0; p < 8; ++p) {
            dkv[p] = __fsub_rn(__fadd_rn(s1_s[p], wq), __fmul_rn(2.0f, (float)acc[p]));
            kiv[p] = t;
        }
#pragma unroll
        for (int step = 1; step < 64; step <<= 1) {
#pragma unroll
            for (int p = 0; p < 8; ++p) {
                float od = __shfl_xor(dkv[p], step);
                int   oi = __shfl_xor(kiv[p], step);
                if (od < dkv[p] || (od == dkv[p] && oi < kiv[p])) { dkv[p] = od; kiv[p] = oi; }
            }
        }
        if (lane == 0) {
#pragma unroll
            for (int p = 0; p < 8; ++p) { wd[wid][p] = dkv[p]; wi[wid][p] = kiv[p]; }
        }
        __syncthreads();
        if (t < 8) {
            float bd = wd[0][t];
            int   bi = wi[0][t];
#pragma unroll
            for (int sq = 1; sq < 16; ++sq) {
                float ad = wd[sq][t];
                int   ai = wi[sq][t];
                if (ad < bd || (ad == bd && ai < bi)) { bd = ad; bi = ai; }
            }
            if (base + t < nf) idx[np_s[t]] = bi;
        }
    }
}

// ---------- gather + straight-through + loss ----------
__global__ __launch_bounds__(256, 2)
void k_quant(const float* __restrict__ x, const float* __restrict__ w,
             const int* __restrict__ idx, float* __restrict__ qout,
             float* __restrict__ iout, float* __restrict__ loss) {
    __shared__ float wrow[64 * 257];
    __shared__ int lidx[64];
    __shared__ float part[4];
    const int t = threadIdx.x;
    const long n0 = (long)blockIdx.x * 64;
    const int b = (int)(n0 >> 12), hw0 = (int)(n0 & 4095);

    if (t < 64) lidx[t] = idx[n0 + t];
    __syncthreads();
    for (int i = 0; i < 64; ++i) {
        wrow[i * 257 + t] = w[(long)lidx[i] * DIM + t];
    }
    if (t < 64) iout[n0 + t] = (float)lidx[t];
    __syncthreads();

    const int p = t & 63, cg = t >> 6;
    const float* xb = x + (long)b * DIM * HW + hw0;
    float* qb = qout + (long)b * DIM * HW + hw0;
    float lsum = 0.f;
    for (int i = 0; i < 64; ++i) {
        int c = cg * 64 + i;
        float qv = wrow[p * 257 + c];
        long off = (long)c * HW + p;
        float xv = xb[off];
        float diff = __fsub_rn(qv, xv);
        qb[off] = __fadd_rn(xv, diff);
        lsum = __fmaf_rn(diff, diff, lsum);
    }
#pragma unroll
    for (int off = 32; off; off >>= 1) lsum += __shfl_down(lsum, off);
    if ((t & 63) == 0) part[t >> 6] = lsum;
    __syncthreads();
    if (t == 0) {
        float tot = (part[0] + part[1]) + (part[2] + part[3]);
        atomicAdd(loss, tot * (1.25f / 16777216.f));
    }
}

extern "C" void kernel_launch(void* const* d_in, const int* in_sizes, int n_in,
                              void* d_out, int out_size, void* d_ws, size_t ws_size,
                              hipStream_t stream) {
    const float* x = (const float*)d_in[0];
    const float* w = (const float*)d_in[1];

    float* qout = (float*)d_out;
    float* iout = qout + QELEMS;
    float* loss = iout + NPIX;

    char* wp = (char*)d_ws;
    int*   idx     = (int*)wp;      wp += (size_t)NPIX * 4;           // 256KB
    float* wsq     = (float*)wp;    wp += (size_t)NUM_K * 4;          // 4KB
    float* xsq     = (float*)wp;    wp += (size_t)NPIX * 4;           // 256KB
    int4*  pairf   = (int4*)wp;     wp += (size_t)MAX_FLAGS * 16;     // 256KB
    int*   paircnt = (int*)wp;      wp += 256;
    int*   fullf   = (int*)wp;      wp += (size_t)MAX_FLAGS * 4;      // 64KB
    int*   fullcnt = (int*)wp;      wp += 256;
    float* wtr     = (float*)wp;    wp += (size_t)NUM_K * DIM * 4;    // 1MB
    short* whi     = (short*)wp;    wp += (size_t)NUM_K * DIM * 2;    // 512KB
    size_t need = (size_t)(wp - (char*)d_ws);

    k_prep<<<260, 256, 0, stream>>>(w, wsq, wtr, whi, loss, paircnt, fullcnt);

    if (ws_size >= need) {
        k_argmin_mfma<<<1024, 256, 0, stream>>>(x, whi, wsq, xsq, idx,
                                                pairf, paircnt, fullf, fullcnt);
        k_refine_pair<<<2048, 256, 0, stream>>>(x, w, wsq, xsq, pairf, paircnt, idx);
    } else {
        k_xsq<<<NPIX / 256, 256, 0, stream>>>(x, xsq);
        k_argmin_valu<<<NPIX / 64, 256, 0, stream>>>(x, w, wsq, xsq, idx, fullf, fullcnt);
    }
    k_refine_full<<<512, 1024, 0, stream>>>(x, wtr, wsq, xsq, fullf, fullcnt, idx);
    k_quant<<<NPIX / 64, 256, 0, stream>>>(x, w, idx, qout, iout, loss);
}

// Round 16
// 209.121 us; speedup vs baseline: 2.0027x; 1.0713x over previous
//
#include <hip/hip_runtime.h>
#include <math.h>

#define NUM_K 1024
#define DIM 256
#define HW 4096          // 64*64
#define NPIX 65536       // 16*4096
#define QELEMS 16777216  // 16*256*4096
#define MAX_FLAGS 16384

typedef short bf16x8 __attribute__((ext_vector_type(8)));
typedef float f32x4 __attribute__((ext_vector_type(4)));

__device__ __forceinline__ unsigned short f32_to_bf16_rne(float f) {
    unsigned int u = __float_as_uint(f);
    unsigned int r = u + 0x7FFFu + ((u >> 16) & 1u);
    return (unsigned short)(r >> 16);
}

// merge two lex-sorted top-3 states (proven rounds 9-15, absmax 0)
__device__ __forceinline__ void merge3(float& a1d, int& a1i, float& a2d, int& a2i, float& a3d,
                                       float b1d, int b1i, float b2d, int b2i, float b3d) {
    bool bf = (b1d < a1d) || (b1d == a1d && b1i < a1i);
    float r1d = bf ? b1d : a1d; int r1i = bf ? b1i : a1i;
    float n2d = bf ? b2d : a2d; int n2i = bf ? b2i : a2i;
    float o1d = bf ? a1d : b1d; int o1i = bf ? a1i : b1i;
    bool k2 = (n2d < o1d) || (n2d == o1d && n2i < o1i);
    float r2d = k2 ? n2d : o1d; int r2i = k2 ? n2i : o1i;
    float sm3 = bf ? b3d : a3d;
    float o2d = bf ? a2d : b2d;
    float r3d = k2 ? fminf(sm3, o1d) : fminf(n2d, o2d);
    a1d = r1d; a1i = r1i; a2d = r2d; a2i = r2i; a3d = r3d;
}

// ---------------------------------------------------------------------------
// numpy-replicated f32 sum of squares (pairwise SIMD tree, proven rounds 2-15)
// ---------------------------------------------------------------------------
__device__ __forceinline__ float np_sumsq_256(const float* __restrict__ p, long stride) {
    float blk0 = 0.f, blk1 = 0.f;
#pragma unroll
    for (int h = 0; h < 2; ++h) {
        const float* base = p + (long)h * 128 * stride;
        float s[16];
#pragma unroll
        for (int L = 0; L < 16; ++L) {
            float a0 = base[(long)(L)       * stride]; a0 = __fmul_rn(a0, a0);
            float a1 = base[(long)(16 + L)  * stride]; a1 = __fmul_rn(a1, a1);
            float a2 = base[(long)(32 + L)  * stride]; a2 = __fmul_rn(a2, a2);
            float a3 = base[(long)(48 + L)  * stride]; a3 = __fmul_rn(a3, a3);
            float a4 = base[(long)(64 + L)  * stride]; a4 = __fmul_rn(a4, a4);
            float a5 = base[(long)(80 + L)  * stride]; a5 = __fmul_rn(a5, a5);
            float a6 = base[(long)(96 + L)  * stride]; a6 = __fmul_rn(a6, a6);
            float a7 = base[(long)(112 + L) * stride]; a7 = __fmul_rn(a7, a7);
            float t1 = __fadd_rn(a0, a1);
            float t2 = __fadd_rn(a2, a3);
            float t3 = __fadd_rn(a4, a5);
            float t4 = __fadd_rn(a6, a7);
            s[L] = __fadd_rn(__fadd_rn(t1, t2), __fadd_rn(t3, t4));
        }
        float c0 = __fadd_rn(s[0], s[8]);
        float c1 = __fadd_rn(s[1], s[9]);
        float c2 = __fadd_rn(s[2], s[10]);
        float c3 = __fadd_rn(s[3], s[11]);
        float c4 = __fadd_rn(s[4], s[12]);
        float c5 = __fadd_rn(s[5], s[13]);
        float c6 = __fadd_rn(s[6], s[14]);
        float c7 = __fadd_rn(s[7], s[15]);
        float d0 = __fadd_rn(c0, c4);
        float d1 = __fadd_rn(c1, c5);
        float d2 = __fadd_rn(c2, c6);
        float d3 = __fadd_rn(c3, c7);
        float e0 = __fadd_rn(d0, d2);
        float e1 = __fadd_rn(d1, d3);
        float r  = __fadd_rn(e0, e1);
        if (h == 0) blk0 = r; else blk1 = r;
    }
    return __fadd_rn(blk0, blk1);
}

// ---------------------------------------------------------------------------
// fused prep: blocks 0..127 wfrag, 128..255 wtrans, 256..259 wsq (+zero init)
// ---------------------------------------------------------------------------
__global__ __launch_bounds__(256)
void k_prep(const float* __restrict__ w, float* __restrict__ wsq,
            float* __restrict__ wtr, short* __restrict__ whi,
            float* __restrict__ loss, int* __restrict__ paircnt, int* __restrict__ fullcnt) {
    const int bk = blockIdx.x;
    const int t = threadIdx.x;
    if (bk < 128) {
        int id = bk * 256 + t;                 // 32768 = 1024 codes * 32 chunks
        int code = id >> 5;
        int c = id & 31;
        const float* src = w + (long)code * DIM + c * 8;
        bf16x8 vh;
#pragma unroll
        for (int j = 0; j < 8; ++j) vh[j] = (short)f32_to_bf16_rne(src[j]);
        int fl = ((c & 3) << 4) | (code & 15);
        long addr = ((((long)(code >> 4) * 8 + (c >> 2)) * 64 + fl) * 8);
        *(bf16x8*)(whi + addr) = vh;
    } else if (bk < 256) {
        int d0 = (bk - 128) * 2;
#pragma unroll
        for (int dd = 0; dd < 2; ++dd) {
            int d = d0 + dd;
#pragma unroll
            for (int kk = 0; kk < 4; ++kk) {
                int k = kk * 256 + t;
                wtr[(long)d * NUM_K + k] = w[(long)k * DIM + d];
            }
        }
    } else {
        int k = (bk - 256) * 256 + t;
        wsq[k] = np_sumsq_256(w + (long)k * DIM, 1);
        if (bk == 256 && t == 0) { *loss = 0.f; *paircnt = 0; *fullcnt = 0; }
    }
}

// fallback-only (main path fuses xsq into argmin)
__global__ __launch_bounds__(256) void k_xsq(const float* __restrict__ x, float* __restrict__ xsq) {
    int n = blockIdx.x * 256 + threadIdx.x;
    int b = n >> 12, hw = n & 4095;
    xsq[n] = np_sumsq_256(x + (long)b * DIM * HW + hw, HW);
}

// ---------------------------------------------------------------------------
// MFMA argmin v16 = round-15 proven kernel + insert trim (n3 via fminf,
// provably equivalent: d3 carries no index, ties immaterial).
// Register law (spill traps #1-#3): acc[4][8]=128 AGPR + 128 VGPR = 256 =
// the 2-wave/SIMD boundary. No state may live across a sweep's MFMA loop.
// ---------------------------------------------------------------------------
#define A_SLOT(ks,m,fl) ((((ks)*4+(m))*64+(fl))*8)

__global__ __launch_bounds__(256, 2)
void k_argmin_mfma(const float* __restrict__ x,
                   const short* __restrict__ whi,
                   const float* __restrict__ wsq, float* __restrict__ xsq,
                   int* __restrict__ idx,
                   int4* __restrict__ pairf, int* __restrict__ paircnt,
                   int* __restrict__ fullf, int* __restrict__ fullcnt) {
    __shared__ short ahi[8 * 4 * 64 * 8];      // 32KB [ks][m][fl][j]
    __shared__ float xpart[4 * 16 * 64];       // 16KB [q][L][px] numpy-tree partials
    __shared__ float xsq_s[64];
    __shared__ float cd1[4][64], cd2[4][64], cd3[4][64];
    __shared__ int   ci1[4][64], ci2[4][64];

    const int t = threadIdx.x;
    const int lane = t & 63;
    const int q = t >> 6;
    const int tile = blockIdx.x;               // 1024 tiles of 64 px
    const int b = tile >> 6;
    const int hw0 = (tile & 63) * 64;
    const long px0 = (long)tile * 64;
    const float* xb = x + (long)b * (DIM * HW) + hw0 + lane;

    // ---- stage A (once) + numpy-tree square partials ----
    {
        float tmp[16], part[16];
#pragma unroll
        for (int i = 0; i < 8; ++i) {
            int c = q * 8 + i;                 // d-chunk: d = c*8 + jj
            float v[8];
#pragma unroll
            for (int jj = 0; jj < 8; ++jj) v[jj] = xb[(long)(c * 8 + jj) * HW];
            bf16x8 vh;
#pragma unroll
            for (int jj = 0; jj < 8; ++jj) vh[jj] = (short)f32_to_bf16_rne(v[jj]);
            int slot = A_SLOT(c >> 2, lane >> 4, ((c & 3) << 4) | (lane & 15));
            *(bf16x8*)(ahi + slot) = vh;
            const int kp = i >> 1;
#pragma unroll
            for (int jj = 0; jj < 8; ++jj) {
                int L = ((i & 1) << 3) | jj;
                float a = __fmul_rn(v[jj], v[jj]);
                if (kp == 0) tmp[L] = a;
                else if (kp == 1) part[L] = __fadd_rn(tmp[L], a);
                else if (kp == 2) tmp[L] = a;
                else part[L] = __fadd_rn(part[L], __fadd_rn(tmp[L], a));
            }
        }
#pragma unroll
        for (int L = 0; L < 16; ++L) xpart[(q * 16 + L) * 64 + lane] = part[L];
    }
    __syncthreads();

    // ---- finisher: complete np_sumsq per pixel (t<64), LDS + global ----
    if (t < 64) {
        float blk[2];
#pragma unroll
        for (int h = 0; h < 2; ++h) {
            float s[16];
#pragma unroll
            for (int L = 0; L < 16; ++L)
                s[L] = __fadd_rn(xpart[((2 * h) * 16 + L) * 64 + t],
                                 xpart[((2 * h + 1) * 16 + L) * 64 + t]);
            float c0 = __fadd_rn(s[0], s[8]);
            float c1 = __fadd_rn(s[1], s[9]);
            float c2 = __fadd_rn(s[2], s[10]);
            float c3 = __fadd_rn(s[3], s[11]);
            float c4 = __fadd_rn(s[4], s[12]);
            float c5 = __fadd_rn(s[5], s[13]);
            float c6 = __fadd_rn(s[6], s[14]);
            float c7 = __fadd_rn(s[7], s[15]);
            float d0 = __fadd_rn(c0, c4);
            float d1 = __fadd_rn(c1, c5);
            float d2 = __fadd_rn(c2, c6);
            float d3 = __fadd_rn(c3, c7);
            float e0 = __fadd_rn(d0, d2);
            float e1 = __fadd_rn(d1, d3);
            blk[h] = __fadd_rn(e0, e1);
        }
        float v = __fadd_rn(blk[0], blk[1]);
        xsq_s[t] = v;
        xsq[px0 + t] = v;                      // for the exact-refine kernel
    }
    __syncthreads();

    // ---- two K-sweeps; per-lane top-3 each, butterfly + LDS merge PER SWEEP ----
#pragma unroll
    for (int s = 0; s < 2; ++s) {
        const int ct0 = s * 32 + q * 8;
        f32x4 acc[4][8];
#pragma unroll
        for (int m = 0; m < 4; ++m)
#pragma unroll
            for (int n = 0; n < 8; ++n) acc[m][n] = (f32x4){0.f, 0.f, 0.f, 0.f};

#define BADDR(i) ((((long)(ct0 + ((i) & 7)) * 8 + ((i) >> 3)) * 64 + lane) * 8)
        bf16x8 bring[4];
#pragma unroll
        for (int i = 0; i < 4; ++i) bring[i] = *(const bf16x8*)(whi + BADDR(i));

        bf16x8 ah[4];
#pragma unroll
        for (int i = 0; i < 64; ++i) {
            const int ks = i >> 3;
            const int n = i & 7;
            if (n == 0) {
#pragma unroll
                for (int m = 0; m < 4; ++m)
                    ah[m] = *(const bf16x8*)(ahi + A_SLOT(ks, m, lane));
            }
            bf16x8 bcur = bring[i & 3];
            if (i + 4 < 64) bring[i & 3] = *(const bf16x8*)(whi + BADDR(i + 4));
#pragma unroll
            for (int m = 0; m < 4; ++m)
                acc[m][n] = __builtin_amdgcn_mfma_f32_16x16x32_bf16(ah[m], bcur, acc[m][n], 0, 0, 0);
        }
#undef BADDR

        // epilogue: np-grid dist + per-lane top-3 (insert-trimmed)
        const int rbase = (lane >> 4) * 4;
        float s1v[4][4];
#pragma unroll
        for (int m = 0; m < 4; ++m)
#pragma unroll
            for (int r = 0; r < 4; ++r) s1v[m][r] = xsq_s[16 * m + rbase + r];

        float e1d[4][4], e2d[4][4], e3d[4][4];
        int   e1i[4][4], e2i[4][4];
#pragma unroll
        for (int m = 0; m < 4; ++m)
#pragma unroll
            for (int r = 0; r < 4; ++r) {
                e1d[m][r] = INFINITY; e2d[m][r] = INFINITY; e3d[m][r] = INFINITY;
                e1i[m][r] = 0; e2i[m][r] = 0;
            }

#pragma unroll
        for (int n = 0; n < 8; ++n) {
            int code = (ct0 + n) * 16 + (lane & 15);
            float wq = wsq[code];
#pragma unroll
            for (int m = 0; m < 4; ++m) {
#pragma unroll
                for (int r = 0; r < 4; ++r) {
                    float tt = __fadd_rn(s1v[m][r], wq);
                    float dist = __fmaf_rn(-2.0f, acc[m][n][r], tt);
                    bool c1 = dist < e1d[m][r];
                    bool c2 = dist < e2d[m][r];
                    float n3 = c2 ? e2d[m][r] : fminf(dist, e3d[m][r]);
                    float n2 = c1 ? e1d[m][r] : (c2 ? dist : e2d[m][r]);
                    int   j2 = c1 ? e1i[m][r] : (c2 ? code : e2i[m][r]);
                    float n1 = c1 ? dist : e1d[m][r];
                    int   j1 = c1 ? code : e1i[m][r];
                    e3d[m][r] = n3; e2d[m][r] = n2; e2i[m][r] = j2;
                    e1d[m][r] = n1; e1i[m][r] = j1;
                }
            }
        }

#pragma unroll
        for (int step = 1; step < 16; step <<= 1) {
#pragma unroll
            for (int m = 0; m < 4; ++m) {
#pragma unroll
                for (int r = 0; r < 4; ++r) {
                    float o1 = __shfl_xor(e1d[m][r], step);
                    int   p1 = __shfl_xor(e1i[m][r], step);
                    float o2 = __shfl_xor(e2d[m][r], step);
                    int   p2 = __shfl_xor(e2i[m][r], step);
                    float o3 = __shfl_xor(e3d[m][r], step);
                    merge3(e1d[m][r], e1i[m][r], e2d[m][r], e2i[m][r], e3d[m][r],
                           o1, p1, o2, p2, o3);
                }
            }
        }

        if ((lane & 15) == 0) {
#pragma unroll
            for (int m = 0; m < 4; ++m) {
#pragma unroll
                for (int r = 0; r < 4; ++r) {
                    int px = 16 * m + rbase + r;
                    if (s == 0) {
                        cd1[q][px] = e1d[m][r]; ci1[q][px] = e1i[m][r];
                        cd2[q][px] = e2d[m][r]; ci2[q][px] = e2i[m][r];
                        cd3[q][px] = e3d[m][r];
                    } else {
                        float a1 = cd1[q][px], a2 = cd2[q][px], a3 = cd3[q][px];
                        int   ai = ci1[q][px], aj = ci2[q][px];
                        merge3(a1, ai, a2, aj, a3,
                               e1d[m][r], e1i[m][r], e2d[m][r], e2i[m][r], e3d[m][r]);
                        cd1[q][px] = a1; ci1[q][px] = ai;
                        cd2[q][px] = a2; ci2[q][px] = aj;
                        cd3[q][px] = a3;
                    }
                }
            }
        }
    }
    __syncthreads();

    // ---- cross-wave merge + classify: done / pair / full ----
    if (t < 64) {
        float d1 = cd1[0][t], d2 = cd2[0][t], d3 = cd3[0][t];
        int   i1 = ci1[0][t], i2 = ci2[0][t];
#pragma unroll
        for (int sq = 1; sq < 4; ++sq) {
            merge3(d1, i1, d2, i2, d3,
                   cd1[sq][t], ci1[sq][t], cd2[sq][t], ci2[sq][t], cd3[sq][t]);
        }
        const long n = px0 + t;
        idx[n] = i1;
        float m = d1 * 2.5e-6f;
        if (__fsub_rn(d3, d1) <= m) {
            int pos = atomicAdd(fullcnt, 1);
            if (pos < MAX_FLAGS) fullf[pos] = (int)n;
        } else if (__fsub_rn(d2, d1) <= m) {
            int pos = atomicAdd(paircnt, 1);
            if (pos < MAX_FLAGS) pairf[pos] = (int4){(int)n, i1, i2, 0};
        }
    }
}

// ---------- fallback VALU argmin (round-2 proven; emits full-flags only) ----------
__global__ __launch_bounds__(256, 2)
void k_argmin_valu(const float* __restrict__ x, const float* __restrict__ w,
                   const float* __restrict__ wsq, const float* __restrict__ xsq,
                   int* __restrict__ idx, int* __restrict__ fullf, int* __restrict__ fullcnt) {
    __shared__ float xs[64 * 257];
    __shared__ float sd1[4][64];
    __shared__ float sd2[4][64];
    __shared__ int   si1[4][64];

    const int t = threadIdx.x;
    const int p = t & 63;
    const int q = t >> 6;
    const long n0 = (long)blockIdx.x * 64;
    const int b = (int)(n0 >> 12);
    const int hw0 = (int)(n0 & 4095);
    const float* xb = x + (long)b * DIM * HW + hw0;

    for (int i = 0; i < 64; ++i) {
        int c = q * 64 + i;
        xs[p * 257 + c] = xb[(long)c * HW + p];
    }
    __syncthreads();

    const float* xrow = xs + p * 257;
    const float s1 = xsq[n0 + p];
    float d1 = INFINITY, d2 = INFINITY;
    int i1 = 0;
    const int kbase = q * 256;
    const float* wq = w + (long)kbase * DIM;
    const float* wsq_q = wsq + kbase;

    for (int kc = 0; kc < 256; kc += 8) {
        float acc[8] = {0.f, 0.f, 0.f, 0.f, 0.f, 0.f, 0.f, 0.f};
        const float* w0 = wq + (long)kc * DIM;
#pragma unroll 2
        for (int d = 0; d < DIM; d += 4) {
            float x0 = xrow[d + 0];
            float x1 = xrow[d + 1];
            float x2 = xrow[d + 2];
            float x3 = xrow[d + 3];
#pragma unroll
            for (int j = 0; j < 8; ++j) {
                const float4 wv = *reinterpret_cast<const float4*>(w0 + j * DIM + d);
                acc[j] = __fmaf_rn(x0, wv.x, acc[j]);
                acc[j] = __fmaf_rn(x1, wv.y, acc[j]);
                acc[j] = __fmaf_rn(x2, wv.z, acc[j]);
                acc[j] = __fmaf_rn(x3, wv.w, acc[j]);
            }
        }
#pragma unroll
        for (int j = 0; j < 8; ++j) {
            float tk = __fadd_rn(s1, wsq_q[kc + j]);
            float dist = __fsub_rn(tk, __fmul_rn(2.0f, acc[j]));
            if (dist < d1) { d2 = d1; d1 = dist; i1 = kbase + kc + j; }
            else if (dist < d2) { d2 = dist; }
        }
    }

    sd1[q][p] = d1; sd2[q][p] = d2; si1[q][p] = i1;
    __syncthreads();
    if (q == 0) {
        float bd1 = sd1[0][p], bd2 = sd2[0][p];
        int bi = si1[0][p];
#pragma unroll
        for (int j = 1; j < 4; ++j) {
            float a1 = sd1[j][p], a2 = sd2[j][p];
            int ai = si1[j][p];
            if (a1 < bd1) { bd2 = fminf(bd1, a2); bd1 = a1; bi = ai; }
            else { bd2 = fminf(bd2, fminf(a1, a2)); }
        }
        const long n = n0 + p;
        idx[n] = bi;
        if (__fsub_rn(bd2, bd1) <= bd1 * 6.0e-7f) {
            int pos = atomicAdd(fullcnt, 1);
            if (pos < MAX_FLAGS) fullf[pos] = (int)n;
        }
    }
}

// ---------------------------------------------------------------------------
// FUSED refine: blocks 0..511 = full path (8 px x 1024 codes, proven r9-15),
// blocks 512..767 = pair path (16 waves/block, one pair-pixel per wave,
// proven r9-15). Per-block path uniformity keeps barriers legal.
// ---------------------------------------------------------------------------
__global__ __launch_bounds__(1024)
void k_refine(const float* __restrict__ x, const float* __restrict__ w,
              const float* __restrict__ wtr,
              const float* __restrict__ wsq, const float* __restrict__ xsq,
              const int4* __restrict__ pairf, const int* __restrict__ paircnt,
              const int* __restrict__ fullf, const int* __restrict__ fullcnt,
              int* __restrict__ idx) {
    const int bk = blockIdx.x;
    const int t = threadIdx.x;
    const int lane = t & 63;
    const int wid = t >> 6;

    if (bk >= 512) {
        // ---- pair path: exact f64 dots for the 2 candidates ----
        int np = *paircnt;
        if (np > MAX_FLAGS) np = MAX_FLAGS;
        for (int fi = (bk - 512) * 16 + wid; fi < np; fi += 256 * 16) {
            int4 f = pairf[fi];
            int n = f.x, c1 = f.y, c2 = f.z;
            int b = n >> 12, hw = n & 4095;
            const float* xp = x + (long)b * (DIM * HW) + hw;
            double xd0 = (double)xp[(long)(lane * 4 + 0) * HW];
            double xd1 = (double)xp[(long)(lane * 4 + 1) * HW];
            double xd2 = (double)xp[(long)(lane * 4 + 2) * HW];
            double xd3 = (double)xp[(long)(lane * 4 + 3) * HW];
            const float4 w1 = *reinterpret_cast<const float4*>(w + (long)c1 * DIM + lane * 4);
            const float4 w2 = *reinterpret_cast<const float4*>(w + (long)c2 * DIM + lane * 4);
            double s1 = fma((double)w1.x, xd0, fma((double)w1.y, xd1,
                        fma((double)w1.z, xd2, (double)w1.w * xd3)));
            double s2 = fma((double)w2.x, xd0, fma((double)w2.y, xd1,
                        fma((double)w2.z, xd2, (double)w2.w * xd3)));
#pragma unroll
            for (int st = 1; st < 64; st <<= 1) {
                s1 += __shfl_xor(s1, st);
                s2 += __shfl_xor(s2, st);
            }
            if (lane == 0) {
                float xq = xsq[n];
                float dk1 = __fsub_rn(__fadd_rn(xq, wsq[c1]), __fmul_rn(2.0f, (float)s1));
                float dk2 = __fsub_rn(__fadd_rn(xq, wsq[c2]), __fmul_rn(2.0f, (float)s2));
                bool take2 = (dk2 < dk1) || (dk2 == dk1 && c2 < c1);
                idx[n] = take2 ? c2 : c1;
            }
        }
        return;
    }

    // ---- full path: 8 px x 1024 codes per block ----
    __shared__ float xsf[DIM][8];       // 8KB
    __shared__ int   np_s[8];
    __shared__ float s1_s[8];
    __shared__ float wd[16][8];
    __shared__ int   wi[16][8];

    int nf = *fullcnt;
    if (nf > MAX_FLAGS) nf = MAX_FLAGS;

    for (int base = bk * 8; base < nf; base += 512 * 8) {
        __syncthreads();
        if (t < 8) {
            int fi = base + t;
            int n = fullf[fi < nf ? fi : (nf - 1)];
            np_s[t] = n;
            s1_s[t] = xsq[n];
        }
        __syncthreads();
#pragma unroll
        for (int e = t; e < 2048; e += 1024) {
            int p = e & 7, d = e >> 3;
            int n = np_s[p];
            xsf[d][p] = x[(long)(n >> 12) * (DIM * HW) + (long)d * HW + (n & 4095)];
        }
        __syncthreads();

        const float wq = wsq[t];
        double acc[8] = {0.0, 0.0, 0.0, 0.0, 0.0, 0.0, 0.0, 0.0};
#pragma unroll 4
        for (int d = 0; d < DIM; ++d) {
            double wk = (double)wtr[(long)d * NUM_K + t];
#pragma unroll
            for (int p = 0; p < 8; ++p) acc[p] = fma(wk, (double)xsf[d][p], acc[p]);
        }

        float dkv[8];
        int   kiv[8];
#pragma unroll
        for (int p = 0; p < 8; ++p) {
            dkv[p] = __fsub_rn(__fadd_rn(s1_s[p], wq), __fmul_rn(2.0f, (float)acc[p]));
            kiv[p] = t;
        }
#pragma unroll
        for (int step = 1; step < 64; step <<= 1) {
#pragma unroll
            for (int p = 0; p < 8; ++p) {
                float od = __shfl_xor(dkv[p], step);
                int   oi = __shfl_xor(kiv[p], step);
                if (od < dkv[p] || (od == dkv[p] && oi < kiv[p])) { dkv[p] = od; kiv[p] = oi; }
            }
        }
        if (lane == 0) {
#pragma unroll
            for (int p = 0; p < 8; ++p) { wd[wid][p] = dkv[p]; wi[wid][p] = kiv[p]; }
        }
        __syncthreads();
        if (t < 8) {
            float bd = wd[0][t];
            int   bi = wi[0][t];
#pragma unroll
            for (int sq = 1; sq < 16; ++sq) {
                float ad = wd[sq][t];
                int   ai = wi[sq][t];
                if (ad < bd || (ad == bd && ai < bi)) { bd = ad; bi = ai; }
            }
            if (base + t < nf) idx[np_s[t]] = bi;
        }
    }
}

// ---------- gather + straight-through + loss ----------
__global__ __launch_bounds__(256, 2)
void k_quant(const float* __restrict__ x, const float* __restrict__ w,
             const int* __restrict__ idx, float* __restrict__ qout,
             float* __restrict__ iout, float* __restrict__ loss) {
    __shared__ float wrow[64 * 257];
    __shared__ int lidx[64];
    __shared__ float part[4];
    const int t = threadIdx.x;
    const long n0 = (long)blockIdx.x * 64;
    const int b = (int)(n0 >> 12), hw0 = (int)(n0 & 4095);

    if (t < 64) lidx[t] = idx[n0 + t];
    __syncthreads();
    for (int i = 0; i < 64; ++i) {
        wrow[i * 257 + t] = w[(long)lidx[i] * DIM + t];
    }
    if (t < 64) iout[n0 + t] = (float)lidx[t];
    __syncthreads();

    const int p = t & 63, cg = t >> 6;
    const float* xb = x + (long)b * DIM * HW + hw0;
    float* qb = qout + (long)b * DIM * HW + hw0;
    float lsum = 0.f;
    for (int i = 0; i < 64; ++i) {
        int c = cg * 64 + i;
        float qv = wrow[p * 257 + c];
        long off = (long)c * HW + p;
        float xv = xb[off];
        float diff = __fsub_rn(qv, xv);
        qb[off] = __fadd_rn(xv, diff);
        lsum = __fmaf_rn(diff, diff, lsum);
    }
#pragma unroll
    for (int off = 32; off; off >>= 1) lsum += __shfl_down(lsum, off);
    if ((t & 63) == 0) part[t >> 6] = lsum;
    __syncthreads();
    if (t == 0) {
        float tot = (part[0] + part[1]) + (part[2] + part[3]);
        atomicAdd(loss, tot * (1.25f / 16777216.f));
    }
}

extern "C" void kernel_launch(void* const* d_in, const int* in_sizes, int n_in,
                              void* d_out, int out_size, void* d_ws, size_t ws_size,
                              hipStream_t stream) {
    const float* x = (const float*)d_in[0];
    const float* w = (const float*)d_in[1];

    float* qout = (float*)d_out;
    float* iout = qout + QELEMS;
    float* loss = iout + NPIX;

    char* wp = (char*)d_ws;
    int*   idx     = (int*)wp;      wp += (size_t)NPIX * 4;           // 256KB
    float* wsq     = (float*)wp;    wp += (size_t)NUM_K * 4;          // 4KB
    float* xsq     = (float*)wp;    wp += (size_t)NPIX * 4;           // 256KB
    int4*  pairf   = (int4*)wp;     wp += (size_t)MAX_FLAGS * 16;     // 256KB
    int*   paircnt = (int*)wp;      wp += 256;
    int*   fullf   = (int*)wp;      wp += (size_t)MAX_FLAGS * 4;      // 64KB
    int*   fullcnt = (int*)wp;      wp += 256;
    float* wtr     = (float*)wp;    wp += (size_t)NUM_K * DIM * 4;    // 1MB
    short* whi     = (short*)wp;    wp += (size_t)NUM_K * DIM * 2;    // 512KB
    size_t need = (size_t)(wp - (char*)d_ws);

    k_prep<<<260, 256, 0, stream>>>(w, wsq, wtr, whi, loss, paircnt, fullcnt);

    if (ws_size >= need) {
        k_argmin_mfma<<<1024, 256, 0, stream>>>(x, whi, wsq, xsq, idx,
                                                pairf, paircnt, fullf, fullcnt);
    } else {
        k_xsq<<<NPIX / 256, 256, 0, stream>>>(x, xsq);
        k_argmin_valu<<<NPIX / 64, 256, 0, stream>>>(x, w, wsq, xsq, idx, fullf, fullcnt);
    }
    k_refine<<<768, 1024, 0, stream>>>(x, w, wtr, wsq, xsq,
                                       pairf, paircnt, fullf, fullcnt, idx);
    k_quant<<<NPIX / 64, 256, 0, stream>>>(x, w, idx, qout, iout, loss);
}